// Round 1
// baseline (36.134 us; speedup 1.0000x reference)
//
#include <hip/hip_runtime.h>

// BFP quantize, NCHW input [32, 256, 56, 56] fp32, block=32 along C, mantissa=5.
// Block elements are strided by H*W in memory; spatial is contiguous, so each
// thread owns 4 consecutive spatial positions (float4) and loops the 32
// channels of its block. All global traffic is coalesced dwordx4.

constexpr int HW  = 56 * 56;   // 3136
constexpr int S4  = HW / 4;    // 784 float4-quads per channel-plane
constexpr int CB  = 8;         // 256 / 32 channel blocks
constexpr int B   = 32;
constexpr int NTHREADS = B * CB * S4;  // 200704
constexpr int BLOCK = 256;

__device__ __forceinline__ void scale_of(float m, float& s, float& r) {
    // m = maxabs of the block (>= 0). Shared exponent e = floor(log2(m)) is
    // just the IEEE biased exponent field for normal m. scale = 2^(e-4).
    unsigned ef = (__float_as_uint(m) >> 23) & 0xFFu;
    if (__builtin_expect(ef > 4u, 1)) {
        s = __uint_as_float((ef - 4u) << 23);    // 2^(e-4), exact
        r = __uint_as_float((258u - ef) << 23);  // 2^-(e-4) = bias 254-(ef-4)
    } else {
        // m == 0 (all-zero block) or absurdly tiny denormal: force q = 0.
        s = 1.0f;
        r = 0.0f;
    }
}

__global__ __launch_bounds__(BLOCK)
void bfp_kernel(const float* __restrict__ in, float* __restrict__ out) {
    int t    = blockIdx.x * BLOCK + threadIdx.x;   // grid sized exactly
    int s4   = t % S4;
    int rest = t / S4;
    int cb   = rest & (CB - 1);
    int b    = rest >> 3;
    size_t base = ((size_t)(b * 256 + cb * 32)) * HW + (size_t)s4 * 4;

    const float* ip = in + base;
    float*       op = out + base;

    float4 v[32];
#pragma unroll
    for (int k = 0; k < 32; ++k)
        v[k] = *reinterpret_cast<const float4*>(ip + (size_t)k * HW);

    float mx = 0.f, my = 0.f, mz = 0.f, mw = 0.f;
#pragma unroll
    for (int k = 0; k < 32; ++k) {
        mx = fmaxf(mx, fabsf(v[k].x));
        my = fmaxf(my, fabsf(v[k].y));
        mz = fmaxf(mz, fabsf(v[k].z));
        mw = fmaxf(mw, fabsf(v[k].w));
    }

    float sx, rx, sy, ry, sz, rz, sw, rw;
    scale_of(mx, sx, rx);
    scale_of(my, sy, ry);
    scale_of(mz, sz, rz);
    scale_of(mw, sw, rw);

#pragma unroll
    for (int k = 0; k < 32; ++k) {
        // q = clip(rint(x / scale), -31, 31); out = q * scale.
        // rintf = round-half-even = jnp.round; mul by 2^p is exact.
        v[k].x = fminf(fmaxf(rintf(v[k].x * rx), -31.f), 31.f) * sx;
        v[k].y = fminf(fmaxf(rintf(v[k].y * ry), -31.f), 31.f) * sy;
        v[k].z = fminf(fmaxf(rintf(v[k].z * rz), -31.f), 31.f) * sz;
        v[k].w = fminf(fmaxf(rintf(v[k].w * rw), -31.f), 31.f) * sw;
        *reinterpret_cast<float4*>(op + (size_t)k * HW) = v[k];
    }
}

extern "C" void kernel_launch(void* const* d_in, const int* in_sizes, int n_in,
                              void* d_out, int out_size, void* d_ws, size_t ws_size,
                              hipStream_t stream) {
    const float* in = (const float*)d_in[0];
    float* out = (float*)d_out;
    bfp_kernel<<<NTHREADS / BLOCK, BLOCK, 0, stream>>>(in, out);
}

// Round 2
// 35.839 us; speedup vs baseline: 1.0082x; 1.0082x over previous
//
#include <hip/hip_runtime.h>

// BFP quantize, NCHW [32, 256, 56, 56] fp32, block=32 along C, mantissa=5.
// Channel-block elements are strided by H*W; spatial is contiguous.
// R2: split each 32-channel block across 4 lane-groups of a wave (8 float4
// per thread), combine maxabs with __shfl_xor(16/32). Cuts live VGPRs (no
// compiler double-read) and 4x the thread count for latency hiding.

constexpr int HW   = 56 * 56;     // 3136
constexpr int S4   = HW / 4;      // 784 float4-quads per plane
constexpr int WPB  = S4 / 16;     // 49 waves per (batch, channel-block)
constexpr int TOTAL_WAVES = 32 * 8 * WPB;      // 12544
constexpr int BLOCK = 256;
constexpr int GRID  = TOTAL_WAVES * 64 / BLOCK; // 3136

__device__ __forceinline__ void scale_of(float m, float& s, float& r) {
    // Shared exponent e = floor(log2(m)) = IEEE exponent field (normal m).
    // scale = 2^(e-4); both scale and 1/scale built exactly from bits.
    unsigned ef = (__float_as_uint(m) >> 23) & 0xFFu;
    if (__builtin_expect(ef > 4u, 1)) {
        s = __uint_as_float((ef - 4u) << 23);    // 2^(e-4)
        r = __uint_as_float((258u - ef) << 23);  // 2^-(e-4)
    } else {                                     // zero block -> q = 0
        s = 1.0f;
        r = 0.0f;
    }
}

__global__ __launch_bounds__(BLOCK)
void bfp_kernel(const float* __restrict__ in, float* __restrict__ out) {
    int t    = blockIdx.x * BLOCK + threadIdx.x;
    int lane = t & 63;
    int w    = t >> 6;
    int s16  = w % WPB;
    int rest = w / WPB;
    int cb   = rest & 7;
    int b    = rest >> 3;
    int q    = lane >> 4;            // channel quarter 0..3
    int s4   = s16 * 16 + (lane & 15);

    size_t base = ((size_t)(b * 256 + cb * 32 + q * 8)) * HW + (size_t)s4 * 4;
    const float* ip = in + base;
    float*       op = out + base;

    float4 v[8];
#pragma unroll
    for (int k = 0; k < 8; ++k)
        v[k] = *reinterpret_cast<const float4*>(ip + (size_t)k * HW);

    float mx = 0.f, my = 0.f, mz = 0.f, mw = 0.f;
#pragma unroll
    for (int k = 0; k < 8; ++k) {
        mx = fmaxf(mx, fabsf(v[k].x));
        my = fmaxf(my, fabsf(v[k].y));
        mz = fmaxf(mz, fabsf(v[k].z));
        mw = fmaxf(mw, fabsf(v[k].w));
    }
    // Combine the 4 channel-quarters (lanes differing in bits 4,5).
#pragma unroll
    for (int mask = 16; mask <= 32; mask <<= 1) {
        mx = fmaxf(mx, __shfl_xor(mx, mask));
        my = fmaxf(my, __shfl_xor(my, mask));
        mz = fmaxf(mz, __shfl_xor(mz, mask));
        mw = fmaxf(mw, __shfl_xor(mw, mask));
    }

    float sx, rx, sy, ry, sz, rz, sw, rw;
    scale_of(mx, sx, rx);
    scale_of(my, sy, ry);
    scale_of(mz, sz, rz);
    scale_of(mw, sw, rw);

#pragma unroll
    for (int k = 0; k < 8; ++k) {
        // q = clip(rint(x/scale), -31, 31); out = q*scale (all pow2-exact,
        // rintf = round-half-even = jnp.round).
        v[k].x = fminf(fmaxf(rintf(v[k].x * rx), -31.f), 31.f) * sx;
        v[k].y = fminf(fmaxf(rintf(v[k].y * ry), -31.f), 31.f) * sy;
        v[k].z = fminf(fmaxf(rintf(v[k].z * rz), -31.f), 31.f) * sz;
        v[k].w = fminf(fmaxf(rintf(v[k].w * rw), -31.f), 31.f) * sw;
        *reinterpret_cast<float4*>(op + (size_t)k * HW) = v[k];
    }
}

extern "C" void kernel_launch(void* const* d_in, const int* in_sizes, int n_in,
                              void* d_out, int out_size, void* d_ws, size_t ws_size,
                              hipStream_t stream) {
    const float* in = (const float*)d_in[0];
    float* out = (float*)d_out;
    bfp_kernel<<<GRID, BLOCK, 0, stream>>>(in, out);
}

// Round 3
// 35.536 us; speedup vs baseline: 1.0168x; 1.0085x over previous
//
#include <hip/hip_runtime.h>

// BFP quantize, NCHW [32, 256, 56, 56] fp32, block=32 along C, mantissa=5.
// R3: same structure as R2 (4 lane-groups x 8 float4 per thread, shfl_xor
// maxabs combine) + NON-TEMPORAL stores so the 102.8 MB output stream
// bypasses cache allocation (fill kernels sustain 7 TB/s with nt writes),
// leaving L3 to the input.

constexpr int HW   = 56 * 56;     // 3136
constexpr int S4   = HW / 4;      // 784 float4-quads per plane
constexpr int WPB  = S4 / 16;     // 49 waves per (batch, channel-block)
constexpr int TOTAL_WAVES = 32 * 8 * WPB;      // 12544
constexpr int BLOCK = 256;
constexpr int GRID  = TOTAL_WAVES * 64 / BLOCK; // 3136

__device__ __forceinline__ void scale_of(float m, float& s, float& r) {
    // Shared exponent e = floor(log2(m)) = IEEE exponent field (normal m).
    unsigned ef = (__float_as_uint(m) >> 23) & 0xFFu;
    if (__builtin_expect(ef > 4u, 1)) {
        s = __uint_as_float((ef - 4u) << 23);    // 2^(e-4)
        r = __uint_as_float((258u - ef) << 23);  // 2^-(e-4)
    } else {                                     // zero block -> q = 0
        s = 1.0f;
        r = 0.0f;
    }
}

__global__ __launch_bounds__(BLOCK)
void bfp_kernel(const float* __restrict__ in, float* __restrict__ out) {
    int t    = blockIdx.x * BLOCK + threadIdx.x;
    int lane = t & 63;
    int w    = t >> 6;
    int s16  = w % WPB;
    int rest = w / WPB;
    int cb   = rest & 7;
    int b    = rest >> 3;
    int q    = lane >> 4;            // channel quarter 0..3
    int s4   = s16 * 16 + (lane & 15);

    size_t base = ((size_t)(b * 256 + cb * 32 + q * 8)) * HW + (size_t)s4 * 4;
    const float* ip = in + base;
    float*       op = out + base;

    float4 v[8];
#pragma unroll
    for (int k = 0; k < 8; ++k)
        v[k] = *reinterpret_cast<const float4*>(ip + (size_t)k * HW);

    float mx = 0.f, my = 0.f, mz = 0.f, mw = 0.f;
#pragma unroll
    for (int k = 0; k < 8; ++k) {
        mx = fmaxf(mx, fabsf(v[k].x));
        my = fmaxf(my, fabsf(v[k].y));
        mz = fmaxf(mz, fabsf(v[k].z));
        mw = fmaxf(mw, fabsf(v[k].w));
    }
#pragma unroll
    for (int mask = 16; mask <= 32; mask <<= 1) {
        mx = fmaxf(mx, __shfl_xor(mx, mask));
        my = fmaxf(my, __shfl_xor(my, mask));
        mz = fmaxf(mz, __shfl_xor(mz, mask));
        mw = fmaxf(mw, __shfl_xor(mw, mask));
    }

    float sx, rx, sy, ry, sz, rz, sw, rw;
    scale_of(mx, sx, rx);
    scale_of(my, sy, ry);
    scale_of(mz, sz, rz);
    scale_of(mw, sw, rw);

#pragma unroll
    for (int k = 0; k < 8; ++k) {
        // q = clip(rint(x/scale), -31, 31); out = q*scale (pow2-exact,
        // rintf = round-half-even = jnp.round).
        float ox = fminf(fmaxf(rintf(v[k].x * rx), -31.f), 31.f) * sx;
        float oy = fminf(fmaxf(rintf(v[k].y * ry), -31.f), 31.f) * sy;
        float oz = fminf(fmaxf(rintf(v[k].z * rz), -31.f), 31.f) * sz;
        float ow = fminf(fmaxf(rintf(v[k].w * rw), -31.f), 31.f) * sw;
        float* p = op + (size_t)k * HW;
        __builtin_nontemporal_store(ox, p + 0);
        __builtin_nontemporal_store(oy, p + 1);
        __builtin_nontemporal_store(oz, p + 2);
        __builtin_nontemporal_store(ow, p + 3);
    }
}

extern "C" void kernel_launch(void* const* d_in, const int* in_sizes, int n_in,
                              void* d_out, int out_size, void* d_ws, size_t ws_size,
                              hipStream_t stream) {
    const float* in = (const float*)d_in[0];
    float* out = (float*)d_out;
    bfp_kernel<<<GRID, BLOCK, 0, stream>>>(in, out);
}